// Round 1
// baseline (204.967 us; speedup 1.0000x reference)
//
#include <hip/hip_runtime.h>

#define BLOCK 256
#define GRID 2048

__global__ __launch_bounds__(BLOCK) void path_loss_count(
    const float* __restrict__ preds,
    const int* __restrict__ targets,
    unsigned int* __restrict__ count,
    int batch) {
    int tid = blockIdx.x * BLOCK + threadIdx.x;
    int stride = gridDim.x * BLOCK;
    unsigned int local = 0;
    for (int row = tid; row < batch; row += stride) {
        const float4* p = reinterpret_cast<const float4*>(preds + (size_t)row * 8);
        float4 a = p[0];
        float4 b = p[1];
        // first-occurrence argmax over 8 (matches jnp.argmax tie-break)
        float m = a.x; int idx = 0;
        if (a.y > m) { m = a.y; idx = 1; }
        if (a.z > m) { m = a.z; idx = 2; }
        if (a.w > m) { m = a.w; idx = 3; }
        if (b.x > m) { m = b.x; idx = 4; }
        if (b.y > m) { m = b.y; idx = 5; }
        if (b.z > m) { m = b.z; idx = 6; }
        if (b.w > m) { m = b.w; idx = 7; }
        int pg = (idx < 3) ? 0 : (idx < 6 ? 1 : 2);
        int t = targets[row];
        int tg = (t < 3) ? 0 : (t < 6 ? 1 : 2);
        local += (unsigned int)(pg != tg);
    }
    // wave64 butterfly reduce
    #pragma unroll
    for (int off = 32; off > 0; off >>= 1)
        local += __shfl_down(local, off, 64);
    __shared__ unsigned int lds[BLOCK / 64];
    int lane = threadIdx.x & 63;
    int wave = threadIdx.x >> 6;
    if (lane == 0) lds[wave] = local;
    __syncthreads();
    if (threadIdx.x == 0) {
        unsigned int s = 0;
        #pragma unroll
        for (int i = 0; i < BLOCK / 64; ++i) s += lds[i];
        atomicAdd(count, s);
    }
}

__global__ void path_loss_finalize(const unsigned int* __restrict__ count,
                                   float* __restrict__ out, int batch) {
    out[0] = (float)((double)(*count) / (double)batch);
}

extern "C" void kernel_launch(void* const* d_in, const int* in_sizes, int n_in,
                              void* d_out, int out_size, void* d_ws, size_t ws_size,
                              hipStream_t stream) {
    const float* preds = (const float*)d_in[0];
    const int* targets = (const int*)d_in[1];
    int batch = in_sizes[1];  // 4194304 rows
    unsigned int* count = (unsigned int*)d_ws;

    hipMemsetAsync(count, 0, sizeof(unsigned int), stream);
    path_loss_count<<<GRID, BLOCK, 0, stream>>>(preds, targets, count, batch);
    path_loss_finalize<<<1, 1, 0, stream>>>(count, (float*)d_out, batch);
}